// Round 1
// baseline (13128.410 us; speedup 1.0000x reference)
//
#include <hip/hip_runtime.h>
#include <cstdint>
#include <cstddef>

// Problem dims
#define VV  32000
#define DD  1024
#define HH  1024
#define LL  2
#define BB  64
#define SS  256
#define G4  4096   // 4*H

typedef __attribute__((ext_vector_type(8))) short short8;
typedef __attribute__((ext_vector_type(4))) float f32x4;
typedef unsigned short u16;
typedef unsigned int u32;

__device__ __forceinline__ u16 f2bf(float f) {
  union { float f; u32 u; } v; v.f = f;
  u32 u = v.u + 0x7fffu + ((v.u >> 16) & 1u);   // RNE
  return (u16)(u >> 16);
}
__device__ __forceinline__ float bf2f(u16 b) {
  union { u32 u; float f; } v; v.u = ((u32)b) << 16;
  return v.f;
}

// ---------------------------------------------------------------- embed
// x0[m=s*64+b][d] = bf16(embedding[inputs[b][s]][d])
__global__ void embed_kernel(const int* __restrict__ inputs,
                             const float* __restrict__ emb,
                             u16* __restrict__ x0) {
  int m = blockIdx.x;              // 0..16383, m = s*64 + b
  int s = m >> 6, b = m & 63;
  int tok = inputs[b * SS + s];
  const f32x4* src = (const f32x4*)(emb + (size_t)tok * DD);
  f32x4 v = src[threadIdx.x];
  u32 lo = (u32)f2bf(v[0]) | ((u32)f2bf(v[1]) << 16);
  u32 hi = (u32)f2bf(v[2]) | ((u32)f2bf(v[3]) << 16);
  u32* dst = (u32*)(x0 + (size_t)m * DD + threadIdx.x * 4);
  dst[0] = lo; dst[1] = hi;
}

// ---------------------------------------------------------------- weight permute+transpose+cast
// W_PT[p][k] = bf16(W[k][n]),  n = g*1024+h,  p = h*4+g   (p-rows k-contiguous)
__global__ void permW_kernel(const float* __restrict__ Wx, const float* __restrict__ Wh,
                             u16* __restrict__ WxPT, u16* __restrict__ WhPT) {
  __shared__ float tl[64][65];
  int bid = blockIdx.x;
  int which = bid >> 10;           // 0,1: Wx l0/l1 ; 2,3: Wh l0/l1
  int tile = bid & 1023;
  int ktile = tile >> 6, ntile = tile & 63;
  const float* src = ((which < 2) ? Wx : Wh) + (size_t)(which & 1) * G4 * 1024;
  u16* dst = ((which < 2) ? WxPT : WhPT) + (size_t)(which & 1) * G4 * 1024;
  int tid = threadIdx.x;
  #pragma unroll
  for (int i = 0; i < 16; ++i) {
    int idx = i * 256 + tid;
    int kk = idx >> 6, nn = idx & 63;
    tl[kk][nn] = src[(size_t)(ktile * 64 + kk) * G4 + ntile * 64 + nn];
  }
  __syncthreads();
  #pragma unroll
  for (int i = 0; i < 16; ++i) {
    int idx = i * 256 + tid;
    int nn = idx >> 6, kk = idx & 63;
    int n = ntile * 64 + nn;
    int p = ((n & 1023) << 2) | (n >> 10);
    dst[(size_t)p * 1024 + ktile * 64 + kk] = f2bf(tl[kk][nn]);
  }
}

// bP[l][p] = b[l][n(p)]
__global__ void permB_kernel(const float* __restrict__ bb, float* __restrict__ bP) {
  int idx = blockIdx.x * 256 + threadIdx.x;  // 8192
  int l = idx >> 12, p = idx & 4095;
  int h = p >> 2, g = p & 3;
  bP[idx] = bb[l * G4 + g * 1024 + h];
}

// ---------------------------------------------------------------- xg GEMM (m97 structure)
__device__ __forceinline__ void gld_lds16(const void* g, void* l) {
  __builtin_amdgcn_global_load_lds((const __attribute__((address_space(1))) unsigned int*)g,
                                   (__attribute__((address_space(3))) unsigned int*)l, 16, 0, 0);
}

// C[m][p] = A[m][:] @ W_PT[p][:]^T + bP[p]   (A bf16 [16384][1024], W_PT bf16 [4096][1024])
__global__ __launch_bounds__(256) void gemm_xg(
    const u16* __restrict__ A, const u16* __restrict__ W,
    const float* __restrict__ bP, float* Cf, u16* Cb, int out_f32) {
  __shared__ u16 As[128 * 32];
  __shared__ u16 Bs[128 * 32];
  const int tid = threadIdx.x;
  const int wave = tid >> 6, lane = tid & 63;
  const int bid = blockIdx.x;
  const int nt = bid & 31, mt = bid >> 5;     // 32 N-tiles, 128 M-tiles
  const u16* Ap = A + (size_t)mt * 128 * 1024;
  const u16* Wp = W + (size_t)nt * 128 * 1024;
  f32x4 acc[4][4];
  #pragma unroll
  for (int i = 0; i < 4; ++i)
    #pragma unroll
    for (int j = 0; j < 4; ++j) acc[i][j] = (f32x4){0.f, 0.f, 0.f, 0.f};
  const int wm = wave >> 1, wn = wave & 1;
  const int r16 = lane & 15, oct = lane >> 4;
  for (int k0 = 0; k0 < 1024; k0 += 32) {
    #pragma unroll
    for (int issue = 0; issue < 2; ++issue) {
      int cb = issue * 256 + wave * 64;       // wave-uniform chunk base
      int c = cb + lane;                      // 16B chunk id: row=c>>2, kq=c&3
      gld_lds16(Ap + (size_t)(c >> 2) * 1024 + k0 + (c & 3) * 8, As + (size_t)cb * 8);
      gld_lds16(Wp + (size_t)(c >> 2) * 1024 + k0 + (c & 3) * 8, Bs + (size_t)cb * 8);
    }
    asm volatile("s_waitcnt vmcnt(0)" ::: "memory");
    __syncthreads();
    short8 af[4], bfr[4];
    #pragma unroll
    for (int i = 0; i < 4; ++i)
      af[i] = *(const short8*)(As + (wm * 64 + i * 16 + r16) * 32 + oct * 8);
    #pragma unroll
    for (int j = 0; j < 4; ++j)
      bfr[j] = *(const short8*)(Bs + (wn * 64 + j * 16 + r16) * 32 + oct * 8);
    #pragma unroll
    for (int i = 0; i < 4; ++i)
      #pragma unroll
      for (int j = 0; j < 4; ++j)
        acc[i][j] = __builtin_amdgcn_mfma_f32_16x16x32_bf16(af[i], bfr[j], acc[i][j], 0, 0, 0);
    __syncthreads();
  }
  #pragma unroll
  for (int j = 0; j < 4; ++j) {
    int n = nt * 128 + wn * 64 + j * 16 + r16;
    float bias = bP[n];
    #pragma unroll
    for (int i = 0; i < 4; ++i) {
      int m = mt * 128 + wm * 64 + i * 16 + oct * 4;
      #pragma unroll
      for (int r = 0; r < 4; ++r) {
        float val = acc[i][j][r] + bias;
        if (out_f32) Cf[(size_t)(m + r) * G4 + n] = val;
        else         Cb[(size_t)(m + r) * G4 + n] = f2bf(val);
      }
    }
  }
}

// ---------------------------------------------------------------- grid barrier (agent scope)
__device__ __forceinline__ void grid_barrier(int* cnt, int* gen, int phase, int nblocks) {
  __syncthreads();
  if (threadIdx.x == 0) {
    int arrived = __hip_atomic_fetch_add(cnt, 1, __ATOMIC_ACQ_REL, __HIP_MEMORY_SCOPE_AGENT);
    if (arrived == phase * nblocks + nblocks - 1) {
      __hip_atomic_store(gen, phase + 1, __ATOMIC_RELEASE, __HIP_MEMORY_SCOPE_AGENT);
    } else {
      while (__hip_atomic_load(gen, __ATOMIC_ACQUIRE, __HIP_MEMORY_SCOPE_AGENT) <= phase)
        __builtin_amdgcn_s_sleep(2);
    }
  }
  __syncthreads();
}

// ---------------------------------------------------------------- persistent LSTM recurrence
// grid 256 = 4 batch-groups x 64 col-groups; block 256 thr (4 waves).
// Wave holds its 16 gate-cols of Wh_PT in 128 VGPRs (loaded once).
__global__ __launch_bounds__(256, 1) void recur_kernel(
    const u16* __restrict__ WhPT,   // [4096][1024] this layer
    const float* xgf, const u16* xgb, int xg_f32,   // [16384][4096] (m = t*64+b)
    const int* __restrict__ lengths,
    u16* __restrict__ hbuf,         // [2][64][1024] bf16, double-buffered
    u16* __restrict__ hs_out,       // layer0: [16384][1024] bf16 (m = t*64+b)
    float* __restrict__ x_out,      // layer1: [64][256][1024] f32
    float* __restrict__ c_out, float* __restrict__ h_out,  // [64][1024] f32
    int layer, int* bar_cnt, int* bar_gen) {
  __shared__ u16 hA[16][1032];      // padded (1024+8): 2-way-max LDS banks
  __shared__ float gbuf[16][64];
  __shared__ float xgbuf[16][64];
  __shared__ int len_s[16];
  const int tid = threadIdx.x;
  const int wave = tid >> 6, lane = tid & 63;
  const int bg = blockIdx.x >> 6, cg = blockIdx.x & 63;
  const int r16 = lane & 15, oct = lane >> 4;

  // B-fragments: lane holds WhPT[cg*64 + wave*16 + r16][kk*32 + oct*8 .. +8]
  short8 bfrag[32];
  {
    const u16* wrow = WhPT + (size_t)(cg * 64 + wave * 16 + r16) * 1024 + oct * 8;
    #pragma unroll
    for (int kk = 0; kk < 32; ++kk) bfrag[kk] = *(const short8*)(wrow + kk * 32);
  }
  if (tid < 16) len_s[tid] = lengths[bg * 16 + tid];
  const int b_loc = tid >> 4, hc_loc = tid & 15;
  const int b_glob = bg * 16 + b_loc;
  const int hc_glob = cg * 16 + hc_loc;
  float c_reg = 0.f, h_reg = 0.f;
  hbuf[(size_t)b_glob * 1024 + hc_glob] = 0;   // zero h[0] slice (each elem once grid-wide)

  const int srow = tid >> 4, sch = tid & 15;
  int phase = 0;
  for (int t = 0; t < SS; ++t) {
    grid_barrier(bar_cnt, bar_gen, phase++, 256);   // h[t&1] fully published
    // stage h tile (16 rows x 1024 bf16) into padded LDS, coalesced
    {
      const u16* hsrc = hbuf + (size_t)(t & 1) * (BB * 1024) + (size_t)(bg * 16 + srow) * 1024;
      #pragma unroll
      for (int i = 0; i < 8; ++i) {
        short8 v = *(const short8*)(hsrc + (sch + i * 16) * 8);
        *(short8*)(&hA[srow][(sch + i * 16) * 8]) = v;
      }
      size_t xrow = (size_t)(t * 64 + bg * 16 + srow) * G4 + cg * 64 + sch * 4;
      if (xg_f32) {
        *(f32x4*)(&xgbuf[srow][sch * 4]) = *(const f32x4*)(xgf + xrow);
      } else {
        const u16* s = xgb + xrow;
        f32x4 v; v[0] = bf2f(s[0]); v[1] = bf2f(s[1]); v[2] = bf2f(s[2]); v[3] = bf2f(s[3]);
        *(f32x4*)(&xgbuf[srow][sch * 4]) = v;
      }
    }
    __syncthreads();
    // gates[16b x 16gc] = h_tile @ Wh_slice  (K=1024, 32 MFMAs, B from registers)
    f32x4 acc = (f32x4){0.f, 0.f, 0.f, 0.f};
    #pragma unroll
    for (int kk = 0; kk < 32; ++kk) {
      short8 a = *(const short8*)(&hA[r16][kk * 32 + oct * 8]);
      acc = __builtin_amdgcn_mfma_f32_16x16x32_bf16(a, bfrag[kk], acc, 0, 0, 0);
    }
    #pragma unroll
    for (int r = 0; r < 4; ++r) gbuf[oct * 4 + r][wave * 16 + r16] = acc[r];
    __syncthreads();
    // elementwise LSTM cell: thread owns (b_loc, hc_loc); p_loc = hc_loc*4+g
    float gi = gbuf[b_loc][hc_loc * 4 + 0] + xgbuf[b_loc][hc_loc * 4 + 0];
    float gf = gbuf[b_loc][hc_loc * 4 + 1] + xgbuf[b_loc][hc_loc * 4 + 1];
    float gg = gbuf[b_loc][hc_loc * 4 + 2] + xgbuf[b_loc][hc_loc * 4 + 2];
    float go = gbuf[b_loc][hc_loc * 4 + 3] + xgbuf[b_loc][hc_loc * 4 + 3];
    float si = 1.f / (1.f + expf(-gi));
    float sf = 1.f / (1.f + expf(-gf));
    float so = 1.f / (1.f + expf(-go));
    float c_new = sf * c_reg + si * tanhf(gg);
    float h_new = so * tanhf(c_new);
    if (t < len_s[b_loc]) { c_reg = c_new; h_reg = h_new; }
    hbuf[(size_t)((t + 1) & 1) * (BB * 1024) + (size_t)b_glob * 1024 + hc_glob] = f2bf(h_reg);
    if (layer == 0) hs_out[(size_t)(t * 64 + b_glob) * 1024 + hc_glob] = f2bf(h_reg);
    else            x_out[(size_t)(b_glob * SS + t) * 1024 + hc_glob] = h_reg;
  }
  c_out[(size_t)b_glob * 1024 + hc_glob] = c_reg;
  h_out[(size_t)b_glob * 1024 + hc_glob] = h_reg;
}

// ---------------------------------------------------------------- launch
extern "C" void kernel_launch(void* const* d_in, const int* in_sizes, int n_in,
                              void* d_out, int out_size, void* d_ws, size_t ws_size,
                              hipStream_t stream) {
  const int* inputs  = (const int*)d_in[0];
  const int* lengths = (const int*)d_in[1];
  const float* emb   = (const float*)d_in[3];
  const float* Wx    = (const float*)d_in[4];
  const float* Wh    = (const float*)d_in[5];
  const float* bb    = (const float*)d_in[6];
  float* out = (float*)d_out;

  char* ws = (char*)d_ws;
  size_t off = 0;
  auto alloc = [&](size_t bytes) -> void* {
    void* p = ws + off;
    off = (off + bytes + 255) & ~(size_t)255;
    return p;
  };
  u16* WxPT = (u16*)alloc((size_t)2 * G4 * 1024 * 2);
  u16* WhPT = (u16*)alloc((size_t)2 * G4 * 1024 * 2);
  float* bP = (float*)alloc((size_t)2 * G4 * 4);
  u16* x0   = (u16*)alloc((size_t)16384 * 1024 * 2);
  u16* hs0  = (u16*)alloc((size_t)16384 * 1024 * 2);
  u16* hbuf = (u16*)alloc((size_t)2 * BB * 1024 * 2);
  int* bar  = (int*)alloc(64);
  size_t xg_f32_bytes = (size_t)16384 * G4 * 4;
  int xg_f32 = (ws_size > off) && ((ws_size - off) >= xg_f32_bytes);
  float* xgf = (float*)(ws + off);
  u16* xgb   = (u16*)(ws + off);

  hipMemsetAsync(bar, 0, 64, stream);
  embed_kernel<<<dim3(16384), dim3(256), 0, stream>>>(inputs, emb, x0);
  permW_kernel<<<dim3(4096), dim3(256), 0, stream>>>(Wx, Wh, WxPT, WhPT);
  permB_kernel<<<dim3(32), dim3(256), 0, stream>>>(bb, bP);

  float* cs_base = out + (size_t)BB * SS * HH;
  float* hs_base = cs_base + (size_t)LL * BB * HH;

  for (int layer = 0; layer < 2; ++layer) {
    const u16* Aten = (layer == 0) ? x0 : hs0;
    gemm_xg<<<dim3(4096), dim3(256), 0, stream>>>(
        Aten, WxPT + (size_t)layer * G4 * 1024, bP + layer * G4, xgf, xgb, xg_f32);
    const u16* Whl = WhPT + (size_t)layer * G4 * 1024;
    float* c_out_p = cs_base + (size_t)layer * BB * HH;
    float* h_out_p = hs_base + (size_t)layer * BB * HH;
    int* cnt = bar + layer * 2;
    int* gen = bar + layer * 2 + 1;
    const float* xgf_c = xgf; const u16* xgb_c = xgb;
    void* args[] = { (void*)&Whl, (void*)&xgf_c, (void*)&xgb_c, (void*)&xg_f32,
                     (void*)&lengths, (void*)&hbuf, (void*)&hs0, (void*)&out,
                     (void*)&c_out_p, (void*)&h_out_p, (void*)&layer,
                     (void*)&cnt, (void*)&gen };
    hipLaunchCooperativeKernel((void*)recur_kernel, dim3(256), dim3(256), args, 0, stream);
  }
}

// Round 2
// 4275.450 us; speedup vs baseline: 3.0706x; 3.0706x over previous
//
#include <hip/hip_runtime.h>
#include <cstdint>
#include <cstddef>

// Problem dims
#define VV  32000
#define DD  1024
#define HH  1024
#define LL  2
#define BB  64
#define SS  256
#define G4  4096   // 4*H

typedef __attribute__((ext_vector_type(8))) short short8;
typedef __attribute__((ext_vector_type(4))) float f32x4;
typedef unsigned short u16;
typedef unsigned int u32;

__device__ __forceinline__ u16 f2bf(float f) {
  union { float f; u32 u; } v; v.f = f;
  u32 u = v.u + 0x7fffu + ((v.u >> 16) & 1u);   // RNE
  return (u16)(u >> 16);
}
__device__ __forceinline__ float bf2f(u16 b) {
  union { u32 u; float f; } v; v.u = ((u32)b) << 16;
  return v.f;
}
__device__ __forceinline__ float sigm(float x) { return 1.f / (1.f + __expf(-x)); }
__device__ __forceinline__ float tanh_fast(float x) {
  float e = __expf(2.f * x);
  return (e - 1.f) / (e + 1.f);
}

// ---------------------------------------------------------------- embed
__global__ void embed_kernel(const int* __restrict__ inputs,
                             const float* __restrict__ emb,
                             u16* __restrict__ x0) {
  int m = blockIdx.x;              // 0..16383, m = s*64 + b
  int s = m >> 6, b = m & 63;
  int tok = inputs[b * SS + s];
  const f32x4* src = (const f32x4*)(emb + (size_t)tok * DD);
  f32x4 v = src[threadIdx.x];
  u32 lo = (u32)f2bf(v[0]) | ((u32)f2bf(v[1]) << 16);
  u32 hi = (u32)f2bf(v[2]) | ((u32)f2bf(v[3]) << 16);
  u32* dst = (u32*)(x0 + (size_t)m * DD + threadIdx.x * 4);
  dst[0] = lo; dst[1] = hi;
}

// ---------------------------------------------------------------- weight permute+transpose+cast
// W_PT[p][k] = bf16(W[k][n]),  n = g*1024+h,  p = h*4+g   (p-rows k-contiguous)
__global__ void permW_kernel(const float* __restrict__ Wx, const float* __restrict__ Wh,
                             u16* __restrict__ WxPT, u16* __restrict__ WhPT) {
  __shared__ float tl[64][65];
  int bid = blockIdx.x;
  int which = bid >> 10;           // 0,1: Wx l0/l1 ; 2,3: Wh l0/l1
  int tile = bid & 1023;
  int ktile = tile >> 6, ntile = tile & 63;
  const float* src = ((which < 2) ? Wx : Wh) + (size_t)(which & 1) * G4 * 1024;
  u16* dst = ((which < 2) ? WxPT : WhPT) + (size_t)(which & 1) * G4 * 1024;
  int tid = threadIdx.x;
  #pragma unroll
  for (int i = 0; i < 16; ++i) {
    int idx = i * 256 + tid;
    int kk = idx >> 6, nn = idx & 63;
    tl[kk][nn] = src[(size_t)(ktile * 64 + kk) * G4 + ntile * 64 + nn];
  }
  __syncthreads();
  #pragma unroll
  for (int i = 0; i < 16; ++i) {
    int idx = i * 256 + tid;
    int nn = idx >> 6, kk = idx & 63;
    int n = ntile * 64 + nn;
    int p = ((n & 1023) << 2) | (n >> 10);
    dst[(size_t)p * 1024 + ktile * 64 + kk] = f2bf(tl[kk][nn]);
  }
}

__global__ void permB_kernel(const float* __restrict__ bb, float* __restrict__ bP) {
  int idx = blockIdx.x * 256 + threadIdx.x;  // 8192
  int l = idx >> 12, p = idx & 4095;
  int h = p >> 2, g = p & 3;
  bP[idx] = bb[l * G4 + g * 1024 + h];
}

// ---------------------------------------------------------------- xg GEMM (m97 structure)
__device__ __forceinline__ void gld_lds16(const void* g, void* l) {
  __builtin_amdgcn_global_load_lds((const __attribute__((address_space(1))) unsigned int*)g,
                                   (__attribute__((address_space(3))) unsigned int*)l, 16, 0, 0);
}

__global__ __launch_bounds__(256) void gemm_xg(
    const u16* __restrict__ A, const u16* __restrict__ W,
    const float* __restrict__ bP, float* Cf, u16* Cb, int out_f32) {
  __shared__ u16 As[128 * 32];
  __shared__ u16 Bs[128 * 32];
  const int tid = threadIdx.x;
  const int wave = tid >> 6, lane = tid & 63;
  const int bid = blockIdx.x;
  const int nt = bid & 31, mt = bid >> 5;     // 32 N-tiles, 128 M-tiles
  const u16* Ap = A + (size_t)mt * 128 * 1024;
  const u16* Wp = W + (size_t)nt * 128 * 1024;
  f32x4 acc[4][4];
  #pragma unroll
  for (int i = 0; i < 4; ++i)
    #pragma unroll
    for (int j = 0; j < 4; ++j) acc[i][j] = (f32x4){0.f, 0.f, 0.f, 0.f};
  const int wm = wave >> 1, wn = wave & 1;
  const int r16 = lane & 15, oct = lane >> 4;
  for (int k0 = 0; k0 < 1024; k0 += 32) {
    #pragma unroll
    for (int issue = 0; issue < 2; ++issue) {
      int cb = issue * 256 + wave * 64;       // wave-uniform chunk base
      int c = cb + lane;                      // 16B chunk id: row=c>>2, kq=c&3
      gld_lds16(Ap + (size_t)(c >> 2) * 1024 + k0 + (c & 3) * 8, As + (size_t)cb * 8);
      gld_lds16(Wp + (size_t)(c >> 2) * 1024 + k0 + (c & 3) * 8, Bs + (size_t)cb * 8);
    }
    asm volatile("s_waitcnt vmcnt(0)" ::: "memory");
    __syncthreads();
    short8 af[4], bfr[4];
    #pragma unroll
    for (int i = 0; i < 4; ++i)
      af[i] = *(const short8*)(As + (wm * 64 + i * 16 + r16) * 32 + oct * 8);
    #pragma unroll
    for (int j = 0; j < 4; ++j)
      bfr[j] = *(const short8*)(Bs + (wn * 64 + j * 16 + r16) * 32 + oct * 8);
    #pragma unroll
    for (int i = 0; i < 4; ++i)
      #pragma unroll
      for (int j = 0; j < 4; ++j)
        acc[i][j] = __builtin_amdgcn_mfma_f32_16x16x32_bf16(af[i], bfr[j], acc[i][j], 0, 0, 0);
    __syncthreads();
  }
  #pragma unroll
  for (int j = 0; j < 4; ++j) {
    int n = nt * 128 + wn * 64 + j * 16 + r16;
    float bias = bP[n];
    #pragma unroll
    for (int i = 0; i < 4; ++i) {
      int m = mt * 128 + wm * 64 + i * 16 + oct * 4;
      #pragma unroll
      for (int r = 0; r < 4; ++r) {
        float val = acc[i][j][r] + bias;
        if (out_f32) Cf[(size_t)(m + r) * G4 + n] = val;
        else         Cb[(size_t)(m + r) * G4 + n] = f2bf(val);
      }
    }
  }
}

// ---------------------------------------------------------------- persistent LSTM recurrence
// grid 256 = 4 batch-groups x 64 col-groups; block 256 thr (4 waves).
// Wave holds its 16 gate-cols of Wh_PT in 128 VGPRs (forced resident).
// Cross-block h exchange: relaxed agent-scope (sc1, LLC-coherent) stores; flag-per-block
// barrier per batch-group; ONE acquire fence (buffer_inv) per step.
__global__ __launch_bounds__(256, 1) void recur_kernel(
    const u16* __restrict__ WhPT,   // [4096][1024] this layer
    const float* xgf, const u16* xgb, int xg_f32,   // [16384][4096] (m = t*64+b)
    const int* __restrict__ lengths,
    u16* __restrict__ hbuf,         // [2][64][1024] bf16, double-buffered
    u16* __restrict__ hs_out,       // layer0: [16384][1024] bf16 (m = t*64+b)
    float* __restrict__ x_out,      // layer1: [64][256][1024] f32
    float* __restrict__ c_out, float* __restrict__ h_out,  // [64][1024] f32
    int layer, int* flags) {        // flags[4][64] this layer
  __shared__ u16 hA[16][1032];      // +8 u16 pad
  __shared__ float gbuf[16][64];
  __shared__ float xgbuf[16][64];
  __shared__ int len_s[16];
  const int tid = threadIdx.x;
  const int wave = tid >> 6, lane = tid & 63;
  const int bg = blockIdx.x >> 6, cg = blockIdx.x & 63;
  const int r16 = lane & 15, oct = lane >> 4;

  // B-fragments: lane holds WhPT[cg*64 + wave*16 + r16][kk*32 + oct*8 .. +8]
  short8 bfrag[32];
  {
    const u16* wrow = WhPT + (size_t)(cg * 64 + wave * 16 + r16) * 1024 + oct * 8;
    #pragma unroll
    for (int kk = 0; kk < 32; ++kk) bfrag[kk] = *(const short8*)(wrow + kk * 32);
    #pragma unroll
    for (int kk = 0; kk < 32; ++kk) asm volatile("" : "+v"(bfrag[kk]));  // pin in VGPRs
  }
  if (tid < 16) len_s[tid] = lengths[bg * 16 + tid];
  const int b_loc = tid >> 4, hc_loc = tid & 15;
  const int b_glob = bg * 16 + b_loc;
  const int hc_glob = cg * 16 + hc_loc;
  float c_reg = 0.f, h_reg = 0.f;
  // zero h[0] slice, coherent (each u32 written by exactly one even thread grid-wide)
  if (!(tid & 1))
    __hip_atomic_store((u32*)(hbuf + (size_t)b_glob * 1024 + hc_glob), 0u,
                       __ATOMIC_RELAXED, __HIP_MEMORY_SCOPE_AGENT);

  int* myflags = flags + bg * 64;
  // prefetch xg[0]
  f32x4 xg_next;
  {
    size_t xrow = (size_t)(0 * 64 + b_glob) * G4 + cg * 64 + hc_loc * 4;
    if (xg_f32) xg_next = *(const f32x4*)(xgf + xrow);
    else {
      const u16* s = xgb + xrow;
      f32x4 v; v[0] = bf2f(s[0]); v[1] = bf2f(s[1]); v[2] = bf2f(s[2]); v[3] = bf2f(s[3]);
      xg_next = v;
    }
  }

  for (int t = 0; t < SS; ++t) {
    // ---- group barrier: publish h[t&1] (sc1 stores drained by syncthreads), flag, poll
    __syncthreads();   // drains vmcnt in every wave -> all h stores at LLC
    if (tid == 0)
      __hip_atomic_store(&myflags[cg], t + 1, __ATOMIC_RELAXED, __HIP_MEMORY_SCOPE_AGENT);
    asm volatile("" ::: "memory");
    if (wave == 0) {
      while (__hip_atomic_load(&myflags[lane], __ATOMIC_RELAXED, __HIP_MEMORY_SCOPE_AGENT) < t + 1)
        __builtin_amdgcn_s_sleep(1);
      __builtin_amdgcn_fence(__ATOMIC_ACQUIRE, "agent");   // one buffer_inv per step
    }
    __syncthreads();
    // ---- stage h tile (16 x 1024 bf16) into padded LDS + xg into LDS
    {
      const u16* hsrc = hbuf + (size_t)(t & 1) * (BB * 1024) + (size_t)b_glob * 1024;
      #pragma unroll
      for (int i = 0; i < 8; ++i)
        *(short8*)(&hA[b_loc][(hc_loc + i * 16) * 8]) = *(const short8*)(hsrc + (hc_loc + i * 16) * 8);
      *(f32x4*)(&xgbuf[b_loc][hc_loc * 4]) = xg_next;
      if (t + 1 < SS) {
        size_t xrow = (size_t)((t + 1) * 64 + b_glob) * G4 + cg * 64 + hc_loc * 4;
        if (xg_f32) xg_next = *(const f32x4*)(xgf + xrow);
        else {
          const u16* s = xgb + xrow;
          f32x4 v; v[0] = bf2f(s[0]); v[1] = bf2f(s[1]); v[2] = bf2f(s[2]); v[3] = bf2f(s[3]);
          xg_next = v;
        }
      }
    }
    __syncthreads();
    // ---- gates[16b x 16gc] = h_tile @ Wh_slice (K=1024, 32 MFMAs, 2 chains)
    f32x4 acc0 = (f32x4){0.f, 0.f, 0.f, 0.f};
    f32x4 acc1 = (f32x4){0.f, 0.f, 0.f, 0.f};
    #pragma unroll
    for (int kk = 0; kk < 16; ++kk) {
      short8 a0 = *(const short8*)(&hA[r16][(2 * kk) * 32 + oct * 8]);
      short8 a1 = *(const short8*)(&hA[r16][(2 * kk + 1) * 32 + oct * 8]);
      acc0 = __builtin_amdgcn_mfma_f32_16x16x32_bf16(a0, bfrag[2 * kk], acc0, 0, 0, 0);
      acc1 = __builtin_amdgcn_mfma_f32_16x16x32_bf16(a1, bfrag[2 * kk + 1], acc1, 0, 0, 0);
    }
    f32x4 acc = acc0 + acc1;
    #pragma unroll
    for (int r = 0; r < 4; ++r) gbuf[oct * 4 + r][wave * 16 + r16] = acc[r];
    __syncthreads();
    // ---- elementwise LSTM cell: thread owns (b_loc, hc_loc)
    f32x4 g = *(const f32x4*)(&gbuf[b_loc][hc_loc * 4]);
    f32x4 xv = *(const f32x4*)(&xgbuf[b_loc][hc_loc * 4]);
    float si = sigm(g[0] + xv[0]);
    float sf = sigm(g[1] + xv[1]);
    float gg = tanh_fast(g[2] + xv[2]);
    float so = sigm(g[3] + xv[3]);
    float c_new = sf * c_reg + si * gg;
    float h_new = so * tanh_fast(c_new);
    if (t < len_s[b_loc]) { c_reg = c_new; h_reg = h_new; }
    // publish h[t+1] coherent: pack 2 cols into u32, even threads store
    u32 hb = (u32)f2bf(h_reg);
    u32 nb = (u32)__shfl_xor((int)hb, 1);
    u32 packed = hb | (nb << 16);
    if (!(tid & 1))
      __hip_atomic_store((u32*)(hbuf + (size_t)((t + 1) & 1) * (BB * 1024) +
                                (size_t)b_glob * 1024 + hc_glob),
                         packed, __ATOMIC_RELAXED, __HIP_MEMORY_SCOPE_AGENT);
    // outputs (nontemporal: keep L2 clean)
    if (layer == 0) {
      if (!(tid & 1))
        __builtin_nontemporal_store(packed,
            (u32*)(hs_out + (size_t)(t * 64 + b_glob) * 1024 + hc_glob));
    } else {
      __builtin_nontemporal_store(h_reg,
          x_out + (size_t)(b_glob * SS + t) * 1024 + hc_glob);
    }
  }
  c_out[(size_t)b_glob * 1024 + hc_glob] = c_reg;
  h_out[(size_t)b_glob * 1024 + hc_glob] = h_reg;
}

// ---------------------------------------------------------------- launch
extern "C" void kernel_launch(void* const* d_in, const int* in_sizes, int n_in,
                              void* d_out, int out_size, void* d_ws, size_t ws_size,
                              hipStream_t stream) {
  const int* inputs  = (const int*)d_in[0];
  const int* lengths = (const int*)d_in[1];
  const float* emb   = (const float*)d_in[3];
  const float* Wx    = (const float*)d_in[4];
  const float* Wh    = (const float*)d_in[5];
  const float* bb    = (const float*)d_in[6];
  float* out = (float*)d_out;

  char* ws = (char*)d_ws;
  size_t off = 0;
  auto alloc = [&](size_t bytes) -> void* {
    void* p = ws + off;
    off = (off + bytes + 255) & ~(size_t)255;
    return p;
  };
  u16* WxPT = (u16*)alloc((size_t)2 * G4 * 1024 * 2);
  u16* WhPT = (u16*)alloc((size_t)2 * G4 * 1024 * 2);
  float* bP = (float*)alloc((size_t)2 * G4 * 4);
  u16* x0   = (u16*)alloc((size_t)16384 * 1024 * 2);
  u16* hs0  = (u16*)alloc((size_t)16384 * 1024 * 2);
  u16* hbuf = (u16*)alloc((size_t)2 * BB * 1024 * 2);
  int* flags = (int*)alloc(2048);          // [2 layers][4 groups][64 blocks]
  size_t xg_f32_bytes = (size_t)16384 * G4 * 4;
  int xg_f32 = (ws_size > off) && ((ws_size - off) >= xg_f32_bytes);
  float* xgf = (float*)(ws + off);
  u16* xgb   = (u16*)(ws + off);

  hipMemsetAsync(flags, 0, 2048, stream);
  embed_kernel<<<dim3(16384), dim3(256), 0, stream>>>(inputs, emb, x0);
  permW_kernel<<<dim3(4096), dim3(256), 0, stream>>>(Wx, Wh, WxPT, WhPT);
  permB_kernel<<<dim3(32), dim3(256), 0, stream>>>(bb, bP);

  float* cs_base = out + (size_t)BB * SS * HH;
  float* hs_base = cs_base + (size_t)LL * BB * HH;

  for (int layer = 0; layer < 2; ++layer) {
    const u16* Aten = (layer == 0) ? x0 : hs0;
    gemm_xg<<<dim3(4096), dim3(256), 0, stream>>>(
        Aten, WxPT + (size_t)layer * G4 * 1024, bP + layer * G4, xgf, xgb, xg_f32);
    const u16* Whl = WhPT + (size_t)layer * G4 * 1024;
    float* c_out_p = cs_base + (size_t)layer * BB * HH;
    float* h_out_p = hs_base + (size_t)layer * BB * HH;
    int* flags_l = flags + layer * 256;
    const float* xgf_c = xgf; const u16* xgb_c = xgb;
    void* args[] = { (void*)&Whl, (void*)&xgf_c, (void*)&xgb_c, (void*)&xg_f32,
                     (void*)&lengths, (void*)&hbuf, (void*)&hs0, (void*)&out,
                     (void*)&c_out_p, (void*)&h_out_p, (void*)&layer,
                     (void*)&flags_l };
    hipLaunchCooperativeKernel((void*)recur_kernel, dim3(256), dim3(256), args, 0, stream);
  }
}

// Round 3
// 2771.117 us; speedup vs baseline: 4.7376x; 1.5429x over previous
//
#include <hip/hip_runtime.h>
#include <cstdint>
#include <cstddef>

// Problem dims
#define VV  32000
#define DD  1024
#define HH  1024
#define LL  2
#define BB  64
#define SS  256
#define G4  4096   // 4*H

typedef __attribute__((ext_vector_type(8))) short short8;
typedef __attribute__((ext_vector_type(4))) float f32x4;
typedef unsigned short u16;
typedef unsigned int u32;

__device__ __forceinline__ u16 f2bf(float f) {
  union { float f; u32 u; } v; v.f = f;
  u32 u = v.u + 0x7fffu + ((v.u >> 16) & 1u);   // RNE
  return (u16)(u >> 16);
}
__device__ __forceinline__ float bf2f(u16 b) {
  union { u32 u; float f; } v; v.u = ((u32)b) << 16;
  return v.f;
}
__device__ __forceinline__ float sigm(float x) { return 1.f / (1.f + __expf(-x)); }
__device__ __forceinline__ float tanh_fast(float x) {
  // 1 - 2/(e^{2x}+1): no inf/inf NaN for large |x|
  return 1.f - 2.f / (__expf(2.f * x) + 1.f);
}

// ---------------------------------------------------------------- embed
__global__ void embed_kernel(const int* __restrict__ inputs,
                             const float* __restrict__ emb,
                             u16* __restrict__ x0) {
  int m = blockIdx.x;              // 0..16383, m = s*64 + b
  int s = m >> 6, b = m & 63;
  int tok = inputs[b * SS + s];
  const f32x4* src = (const f32x4*)(emb + (size_t)tok * DD);
  f32x4 v = src[threadIdx.x];
  u32 lo = (u32)f2bf(v[0]) | ((u32)f2bf(v[1]) << 16);
  u32 hi = (u32)f2bf(v[2]) | ((u32)f2bf(v[3]) << 16);
  u32* dst = (u32*)(x0 + (size_t)m * DD + threadIdx.x * 4);
  dst[0] = lo; dst[1] = hi;
}

// ---------------------------------------------------------------- weight permute+transpose+cast
// W_PT[p][k] = bf16(W[k][n]),  n = g*1024+h,  p = h*4+g   (p-rows k-contiguous)
__global__ void permW_kernel(const float* __restrict__ Wx, const float* __restrict__ Wh,
                             u16* __restrict__ WxPT, u16* __restrict__ WhPT) {
  __shared__ float tl[64][65];
  int bid = blockIdx.x;
  int which = bid >> 10;           // 0,1: Wx l0/l1 ; 2,3: Wh l0/l1
  int tile = bid & 1023;
  int ktile = tile >> 6, ntile = tile & 63;
  const float* src = ((which < 2) ? Wx : Wh) + (size_t)(which & 1) * G4 * 1024;
  u16* dst = ((which < 2) ? WxPT : WhPT) + (size_t)(which & 1) * G4 * 1024;
  int tid = threadIdx.x;
  #pragma unroll
  for (int i = 0; i < 16; ++i) {
    int idx = i * 256 + tid;
    int kk = idx >> 6, nn = idx & 63;
    tl[kk][nn] = src[(size_t)(ktile * 64 + kk) * G4 + ntile * 64 + nn];
  }
  __syncthreads();
  #pragma unroll
  for (int i = 0; i < 16; ++i) {
    int idx = i * 256 + tid;
    int nn = idx >> 6, kk = idx & 63;
    int n = ntile * 64 + nn;
    int p = ((n & 1023) << 2) | (n >> 10);
    dst[(size_t)p * 1024 + ktile * 64 + kk] = f2bf(tl[kk][nn]);
  }
}

__global__ void permB_kernel(const float* __restrict__ bb, float* __restrict__ bP) {
  int idx = blockIdx.x * 256 + threadIdx.x;  // 8192
  int l = idx >> 12, p = idx & 4095;
  int h = p >> 2, g = p & 3;
  bP[idx] = bb[l * G4 + g * 1024 + h];
}

// ---------------------------------------------------------------- xg GEMM (m97 structure)
__device__ __forceinline__ void gld_lds16(const void* g, void* l) {
  __builtin_amdgcn_global_load_lds((const __attribute__((address_space(1))) unsigned int*)g,
                                   (__attribute__((address_space(3))) unsigned int*)l, 16, 0, 0);
}

__global__ __launch_bounds__(256) void gemm_xg(
    const u16* __restrict__ A, const u16* __restrict__ W,
    const float* __restrict__ bP, float* Cf, u16* Cb, int out_f32) {
  __shared__ u16 As[128 * 32];
  __shared__ u16 Bs[128 * 32];
  const int tid = threadIdx.x;
  const int wave = tid >> 6, lane = tid & 63;
  const int bid = blockIdx.x;
  const int nt = bid & 31, mt = bid >> 5;     // 32 N-tiles, 128 M-tiles
  const u16* Ap = A + (size_t)mt * 128 * 1024;
  const u16* Wp = W + (size_t)nt * 128 * 1024;
  f32x4 acc[4][4];
  #pragma unroll
  for (int i = 0; i < 4; ++i)
    #pragma unroll
    for (int j = 0; j < 4; ++j) acc[i][j] = (f32x4){0.f, 0.f, 0.f, 0.f};
  const int wm = wave >> 1, wn = wave & 1;
  const int r16 = lane & 15, oct = lane >> 4;
  for (int k0 = 0; k0 < 1024; k0 += 32) {
    #pragma unroll
    for (int issue = 0; issue < 2; ++issue) {
      int cb = issue * 256 + wave * 64;       // wave-uniform chunk base
      int c = cb + lane;                      // 16B chunk id: row=c>>2, kq=c&3
      gld_lds16(Ap + (size_t)(c >> 2) * 1024 + k0 + (c & 3) * 8, As + (size_t)cb * 8);
      gld_lds16(Wp + (size_t)(c >> 2) * 1024 + k0 + (c & 3) * 8, Bs + (size_t)cb * 8);
    }
    asm volatile("s_waitcnt vmcnt(0)" ::: "memory");
    __syncthreads();
    short8 af[4], bfr[4];
    #pragma unroll
    for (int i = 0; i < 4; ++i)
      af[i] = *(const short8*)(As + (wm * 64 + i * 16 + r16) * 32 + oct * 8);
    #pragma unroll
    for (int j = 0; j < 4; ++j)
      bfr[j] = *(const short8*)(Bs + (wn * 64 + j * 16 + r16) * 32 + oct * 8);
    #pragma unroll
    for (int i = 0; i < 4; ++i)
      #pragma unroll
      for (int j = 0; j < 4; ++j)
        acc[i][j] = __builtin_amdgcn_mfma_f32_16x16x32_bf16(af[i], bfr[j], acc[i][j], 0, 0, 0);
    __syncthreads();
  }
  #pragma unroll
  for (int j = 0; j < 4; ++j) {
    int n = nt * 128 + wn * 64 + j * 16 + r16;
    float bias = bP[n];
    #pragma unroll
    for (int i = 0; i < 4; ++i) {
      int m = mt * 128 + wm * 64 + i * 16 + oct * 4;
      #pragma unroll
      for (int r = 0; r < 4; ++r) {
        float val = acc[i][j][r] + bias;
        if (out_f32) Cf[(size_t)(m + r) * G4 + n] = val;
        else         Cb[(size_t)(m + r) * G4 + n] = f2bf(val);
      }
    }
  }
}

// ---------------------------------------------------------------- persistent LSTM recurrence
// grid 256 = 4 batch-groups x 64 col-groups; block 256 thr (4 waves).
// Wave holds its 16 gate-cols of Wh_PT in 128 AGPRs ("a"-pinned, MFMA reads B from AGPR).
// h exchange via LLC: sc1 stores (atomic relaxed agent) + sc1 loads (inline asm).
// NO acquire fence -> per-XCD L2 never invalidated (stays warm for xg).
__global__ __launch_bounds__(256, 1) void recur_kernel(
    const u16* __restrict__ WhPT,   // [4096][1024] this layer
    const float* xgf, const u16* xgb, int xg_f32,   // [16384][4096] (m = t*64+b)
    const int* __restrict__ lengths,
    u16* __restrict__ hbuf,         // [2][64][1024] bf16, double-buffered
    u16* __restrict__ hs_out,       // layer0: [16384][1024] bf16 (m = t*64+b)
    float* __restrict__ x_out,      // layer1: [64][256][1024] f32
    float* __restrict__ c_out, float* __restrict__ h_out,  // [64][1024] f32
    int layer, int* flags) {        // flags[4][64] this layer
  __shared__ u16 hA[16][1032];      // +8 u16 pad
  __shared__ float gbuf[16][64];
  __shared__ float xgbuf[16][64];
  __shared__ int len_s[16];
  const int tid = threadIdx.x;
  const int wave = tid >> 6, lane = tid & 63;
  const int bg = blockIdx.x >> 6, cg = blockIdx.x & 63;
  const int r16 = lane & 15, oct = lane >> 4;

  // B-fragments: lane holds WhPT[cg*64 + wave*16 + r16][kk*32 + oct*8 .. +8]
  // Pinned into AGPRs: asm output cannot be rematerialized from memory.
  short8 bfrag[32];
  {
    const u16* wrow = WhPT + (size_t)(cg * 64 + wave * 16 + r16) * 1024 + oct * 8;
    #pragma unroll
    for (int kk = 0; kk < 32; ++kk) bfrag[kk] = *(const short8*)(wrow + kk * 32);
    #pragma unroll
    for (int kk = 0; kk < 32; ++kk) asm volatile("" : "+a"(bfrag[kk]));
  }
  if (tid < 16) len_s[tid] = lengths[bg * 16 + tid];
  const int b_loc = tid >> 4, hc_loc = tid & 15;
  const int b_glob = bg * 16 + b_loc;
  const int hc_glob = cg * 16 + hc_loc;
  float c_reg = 0.f, h_reg = 0.f;
  // zero h[0] slice, coherent (each u32 written by exactly one even thread grid-wide)
  if (!(tid & 1))
    __hip_atomic_store((u32*)(hbuf + (size_t)b_glob * 1024 + hc_glob), 0u,
                       __ATOMIC_RELAXED, __HIP_MEMORY_SCOPE_AGENT);

  int* myflags = flags + bg * 64;
  // prefetch xg[0]
  f32x4 xg_next;
  {
    size_t xrow = (size_t)(0 * 64 + b_glob) * G4 + cg * 64 + hc_loc * 4;
    if (xg_f32) xg_next = *(const f32x4*)(xgf + xrow);
    else {
      const u16* s = xgb + xrow;
      f32x4 v; v[0] = bf2f(s[0]); v[1] = bf2f(s[1]); v[2] = bf2f(s[2]); v[3] = bf2f(s[3]);
      xg_next = v;
    }
  }

  for (int t = 0; t < SS; ++t) {
    // ---- group barrier: publish h[t&1] (sc1 stores drained by syncthreads' vmcnt(0)),
    // flag (sc1), poll peers' flags (sc1 loads see LLC directly -> no fence needed)
    __syncthreads();
    if (tid == 0)
      __hip_atomic_store(&myflags[cg], t + 1, __ATOMIC_RELAXED, __HIP_MEMORY_SCOPE_AGENT);
    if (wave == 0) {
      while (__hip_atomic_load(&myflags[lane], __ATOMIC_RELAXED, __HIP_MEMORY_SCOPE_AGENT) < t + 1)
        __builtin_amdgcn_s_sleep(1);
    }
    __syncthreads();
    // ---- stage h tile (16 x 1024 bf16) into padded LDS via sc1 (LLC-coherent) loads
    {
      const u16* hsrc = hbuf + (size_t)(t & 1) * (BB * 1024) + (size_t)b_glob * 1024;
      unsigned long long addr = (unsigned long long)(hsrc + hc_loc * 8);
      short8 v0, v1, v2, v3, v4, v5, v6, v7;
      asm volatile(
        "global_load_dwordx4 %0, %8, off sc1\n\t"
        "global_load_dwordx4 %1, %8, off offset:256 sc1\n\t"
        "global_load_dwordx4 %2, %8, off offset:512 sc1\n\t"
        "global_load_dwordx4 %3, %8, off offset:768 sc1\n\t"
        "global_load_dwordx4 %4, %8, off offset:1024 sc1\n\t"
        "global_load_dwordx4 %5, %8, off offset:1280 sc1\n\t"
        "global_load_dwordx4 %6, %8, off offset:1536 sc1\n\t"
        "global_load_dwordx4 %7, %8, off offset:1792 sc1\n\t"
        "s_waitcnt vmcnt(0)"
        : "=v"(v0), "=v"(v1), "=v"(v2), "=v"(v3),
          "=v"(v4), "=v"(v5), "=v"(v6), "=v"(v7)
        : "v"(addr) : "memory");
      *(short8*)(&hA[b_loc][(hc_loc +   0) * 8]) = v0;
      *(short8*)(&hA[b_loc][(hc_loc +  16) * 8]) = v1;
      *(short8*)(&hA[b_loc][(hc_loc +  32) * 8]) = v2;
      *(short8*)(&hA[b_loc][(hc_loc +  48) * 8]) = v3;
      *(short8*)(&hA[b_loc][(hc_loc +  64) * 8]) = v4;
      *(short8*)(&hA[b_loc][(hc_loc +  80) * 8]) = v5;
      *(short8*)(&hA[b_loc][(hc_loc +  96) * 8]) = v6;
      *(short8*)(&hA[b_loc][(hc_loc + 112) * 8]) = v7;
      *(f32x4*)(&xgbuf[b_loc][hc_loc * 4]) = xg_next;
      if (t + 1 < SS) {
        size_t xrow = (size_t)((t + 1) * 64 + b_glob) * G4 + cg * 64 + hc_loc * 4;
        if (xg_f32) xg_next = *(const f32x4*)(xgf + xrow);
        else {
          const u16* s = xgb + xrow;
          f32x4 v; v[0] = bf2f(s[0]); v[1] = bf2f(s[1]); v[2] = bf2f(s[2]); v[3] = bf2f(s[3]);
          xg_next = v;
        }
      }
    }
    __syncthreads();
    // ---- gates[16b x 16gc] = h_tile @ Wh_slice (K=1024, 32 MFMAs, 2 chains)
    f32x4 acc0 = (f32x4){0.f, 0.f, 0.f, 0.f};
    f32x4 acc1 = (f32x4){0.f, 0.f, 0.f, 0.f};
    #pragma unroll
    for (int kk = 0; kk < 16; ++kk) {
      short8 a0 = *(const short8*)(&hA[r16][(2 * kk) * 32 + oct * 8]);
      short8 a1 = *(const short8*)(&hA[r16][(2 * kk + 1) * 32 + oct * 8]);
      acc0 = __builtin_amdgcn_mfma_f32_16x16x32_bf16(a0, bfrag[2 * kk], acc0, 0, 0, 0);
      acc1 = __builtin_amdgcn_mfma_f32_16x16x32_bf16(a1, bfrag[2 * kk + 1], acc1, 0, 0, 0);
    }
    f32x4 acc = acc0 + acc1;
    #pragma unroll
    for (int r = 0; r < 4; ++r) gbuf[oct * 4 + r][wave * 16 + r16] = acc[r];
    __syncthreads();
    // ---- elementwise LSTM cell: thread owns (b_loc, hc_loc)
    f32x4 g = *(const f32x4*)(&gbuf[b_loc][hc_loc * 4]);
    f32x4 xv = *(const f32x4*)(&xgbuf[b_loc][hc_loc * 4]);
    float si = sigm(g[0] + xv[0]);
    float sf = sigm(g[1] + xv[1]);
    float gg = tanh_fast(g[2] + xv[2]);
    float so = sigm(g[3] + xv[3]);
    float c_new = sf * c_reg + si * gg;
    float h_new = so * tanh_fast(c_new);
    if (t < len_s[b_loc]) { c_reg = c_new; h_reg = h_new; }
    // publish h[t+1] coherent: pack 2 cols into u32, even threads store
    u32 hb = (u32)f2bf(h_reg);
    u32 nb = (u32)__shfl_xor((int)hb, 1);
    u32 packed = hb | (nb << 16);
    if (!(tid & 1))
      __hip_atomic_store((u32*)(hbuf + (size_t)((t + 1) & 1) * (BB * 1024) +
                                (size_t)b_glob * 1024 + hc_glob),
                         packed, __ATOMIC_RELAXED, __HIP_MEMORY_SCOPE_AGENT);
    // outputs (nontemporal: keep L2 clean)
    if (layer == 0) {
      if (!(tid & 1))
        __builtin_nontemporal_store(packed,
            (u32*)(hs_out + (size_t)(t * 64 + b_glob) * 1024 + hc_glob));
    } else {
      __builtin_nontemporal_store(h_reg,
          x_out + (size_t)(b_glob * SS + t) * 1024 + hc_glob);
    }
  }
  c_out[(size_t)b_glob * 1024 + hc_glob] = c_reg;
  h_out[(size_t)b_glob * 1024 + hc_glob] = h_reg;
}

// ---------------------------------------------------------------- launch
extern "C" void kernel_launch(void* const* d_in, const int* in_sizes, int n_in,
                              void* d_out, int out_size, void* d_ws, size_t ws_size,
                              hipStream_t stream) {
  const int* inputs  = (const int*)d_in[0];
  const int* lengths = (const int*)d_in[1];
  const float* emb   = (const float*)d_in[3];
  const float* Wx    = (const float*)d_in[4];
  const float* Wh    = (const float*)d_in[5];
  const float* bb    = (const float*)d_in[6];
  float* out = (float*)d_out;

  char* ws = (char*)d_ws;
  size_t off = 0;
  auto alloc = [&](size_t bytes) -> void* {
    void* p = ws + off;
    off = (off + bytes + 255) & ~(size_t)255;
    return p;
  };
  u16* WxPT = (u16*)alloc((size_t)2 * G4 * 1024 * 2);
  u16* WhPT = (u16*)alloc((size_t)2 * G4 * 1024 * 2);
  float* bP = (float*)alloc((size_t)2 * G4 * 4);
  u16* x0   = (u16*)alloc((size_t)16384 * 1024 * 2);
  u16* hs0  = (u16*)alloc((size_t)16384 * 1024 * 2);
  u16* hbuf = (u16*)alloc((size_t)2 * BB * 1024 * 2);
  int* flags = (int*)alloc(2048);          // [2 layers][4 groups][64 blocks]
  size_t xg_f32_bytes = (size_t)16384 * G4 * 4;
  int xg_f32 = (ws_size > off) && ((ws_size - off) >= xg_f32_bytes);
  float* xgf = (float*)(ws + off);
  u16* xgb   = (u16*)(ws + off);

  hipMemsetAsync(flags, 0, 2048, stream);
  embed_kernel<<<dim3(16384), dim3(256), 0, stream>>>(inputs, emb, x0);
  permW_kernel<<<dim3(4096), dim3(256), 0, stream>>>(Wx, Wh, WxPT, WhPT);
  permB_kernel<<<dim3(32), dim3(256), 0, stream>>>(bb, bP);

  float* cs_base = out + (size_t)BB * SS * HH;
  float* hs_base = cs_base + (size_t)LL * BB * HH;

  for (int layer = 0; layer < 2; ++layer) {
    const u16* Aten = (layer == 0) ? x0 : hs0;
    gemm_xg<<<dim3(4096), dim3(256), 0, stream>>>(
        Aten, WxPT + (size_t)layer * G4 * 1024, bP + layer * G4, xgf, xgb, xg_f32);
    const u16* Whl = WhPT + (size_t)layer * G4 * 1024;
    float* c_out_p = cs_base + (size_t)layer * BB * HH;
    float* h_out_p = hs_base + (size_t)layer * BB * HH;
    int* flags_l = flags + layer * 256;
    const float* xgf_c = xgf; const u16* xgb_c = xgb;
    void* args[] = { (void*)&Whl, (void*)&xgf_c, (void*)&xgb_c, (void*)&xg_f32,
                     (void*)&lengths, (void*)&hbuf, (void*)&hs0, (void*)&out,
                     (void*)&c_out_p, (void*)&h_out_p, (void*)&layer,
                     (void*)&flags_l };
    hipLaunchCooperativeKernel((void*)recur_kernel, dim3(256), dim3(256), args, 0, stream);
  }
}